// Round 15
// baseline (212.136 us; speedup 1.0000x reference)
//
#include <hip/hip_runtime.h>

// Bilinear backward warp, NCHW f32 — producer/consumer wave specialization.
// Block = 64x32 tile, 1024 threads: waves 0..7 CONSUMERS (4 px/thread,
// gather from LDS + store, no memory waits), waves 8..15 PRODUCERS (stage
// channel plane p+2 via global_load_lds, vmcnt(2) retires p+1, barrier).
// CGB=1 channel/phase, 32 phases, TRIPLE buffer (3 x 16 KB padded planes).
// Rationale: R11/12/13 lockstep phases alternate HBM-storm / LDS-storm
// (HBM 38%, LDS 25%, nothing saturated). Producers keep staging in flight
// CONTINUOUSLY under consumer gather; vmcnt is per-wave so producer counting
// (2 DMA instrs/phase) is exact and consumers never wait on vmcnt at all.
// Staging slots lane-consecutive per wave (R10 lesson); dummy slots land in
// the buffer pad. RAD=4 halo; |flow|>4 pixels take global fallback.

#define TSX 64
#define TSY 32
#define RAD 4
#define LW  (TSX + 2*RAD)      // 72
#define LH  (TSY + 2*RAD)      // 40
#define GPR (LW/4)             // 18 float4 groups per row
#define PLANE (LW*LH)          // 2880 floats = 11520 B
#define NV  (LH*GPR)           // 720 real slots per plane
#define BUFP 4096              // padded buffer stride in floats (16384 B)
#define NTHREADS 1024
#define NCONS 512              // consumer threads (waves 0..7)
#define PXT 4                  // pixels per consumer thread

#define GLOAD_LDS16(g, l)                                                  \
    __builtin_amdgcn_global_load_lds(                                      \
        (const __attribute__((address_space(1))) void*)(g),                \
        (__attribute__((address_space(3))) void*)(l), 16, 0, 0)

__global__ __launch_bounds__(NTHREADS, 8) void warp_pc(
    const float* __restrict__ img,
    const float* __restrict__ flow,
    const int* __restrict__ Hp,
    const int* __restrict__ Wp,
    float* __restrict__ out,
    int HW, int C)
{
    __shared__ __align__(16) float lds[3 * BUFP];   // 49152 B

    const int W = *Wp;
    const int H = *Hp;
    const int tilesX = (W + TSX - 1) / TSX;
    const int tilesY = (H + TSY - 1) / TSY;
    const int ntiles = tilesX * tilesY;
    const int bid = blockIdx.x;
    if (bid >= ntiles) return;

    // bijective XCD band swizzle
    const int q = ntiles >> 3, r = ntiles & 7;
    const int xcd = bid & 7, sub = bid >> 3;
    const int t = (xcd < r ? xcd*(q+1) : r*(q+1) + (xcd-r)*q) + sub;

    const int tileY = t / tilesX;
    const int tileX = t - tileY * tilesX;
    const int gx0 = tileX * TSX - RAD;   // ≡ 0 (mod 4)
    const int gy0 = tileY * TSY - RAD;

    const int tid = threadIdx.x;
    const bool consumer = (tid < NCONS);

    const float Wm1 = (float)(W - 1);
    const float Hm1 = (float)(H - 1);

    const bool fast = ((W & 3) == 0) && ((tileX+1)*TSX <= W)
                   && ((tileY+1)*TSY <= H);

    // ---------------- consumer state: 4 px/thread ----------------
    float a0[PXT], a1[PXT], a2[PXT], a3[PXT];
    int   enc[PXT];
    float* optr[PXT];
    int   pixk[PXT];
    if (consumer) {
        #pragma unroll
        for (int j = 0; j < PXT; ++j) {
            const int lpx = j * NCONS + tid;        // 0..2047, lane-consecutive
            const int col = lpx & (TSX - 1);
            const int row = lpx >> 6;               // log2(TSX)=6
            const int gx = tileX * TSX + col;
            const int gy = tileY * TSY + row;
            enc[j] = -2;
            optr[j] = out; pixk[j] = 0;
            a0[j] = a1[j] = a2[j] = a3[j] = 0.f;
            if (gx >= W || gy >= H) continue;
            const int pix = gy * W + gx;
            pixk[j] = pix;
            optr[j] = out + pix;
            const float u = flow[pix];
            const float v = flow[HW + pix];

            // normalize/denormalize round-trip omitted (identity, +-1 ulp)
            const float x = (float)gx + u;
            const float y = (float)gy + v;
            const float x0 = floorf(x), x1 = x0 + 1.0f;
            const float y0 = floorf(y), y1 = y0 + 1.0f;

            const int x0c = (int)fminf(fmaxf(x0, 0.0f), Wm1);
            const int x1c = (int)fminf(fmaxf(x1, 0.0f), Wm1);
            const int y0c = (int)fminf(fmaxf(y0, 0.0f), Hm1);
            const int y1c = (int)fminf(fmaxf(y1, 0.0f), Hm1);

            const float wa = (x1 - x) * (y1 - y);
            const float wb = (x1 - x) * (y - y0);
            const float wc = (x - x0) * (y1 - y);
            const float wd = (x - x0) * (y - y0);

            const int pbx = min(x0c, W - 2);
            const int pby = min(y0c, H - 2);

            const float wlt = (x0c == pbx ? wa : 0.f) + (x1c == pbx ? wc : 0.f);
            const float wht = (x0c != pbx ? wa : 0.f) + (x1c != pbx ? wc : 0.f);
            const float wlb = (x0c == pbx ? wb : 0.f) + (x1c == pbx ? wd : 0.f);
            const float whb = (x0c != pbx ? wb : 0.f) + (x1c != pbx ? wd : 0.f);
            const bool t0 = (y0c == pby), t1 = (y1c == pby);
            a0[j] = (t0 ? wlt : 0.f) + (t1 ? wlb : 0.f);
            a1[j] = (t0 ? wht : 0.f) + (t1 ? whb : 0.f);
            a2[j] = (t0 ? 0.f : wlt) + (t1 ? 0.f : wlb);
            a3[j] = (t0 ? 0.f : wht) + (t1 ? 0.f : whb);

            const int lxp = pbx - gx0;
            const int lyb = pby - gy0;
            enc[j] = (lxp >= 0 && lxp <= LW-2 && lyb >= 0 && lyb <= LH-2)
                   ? (lyb * LW + lxp) : -1;
        }
    }

    // ---------------- producer state: 2 slots/thread ----------------
    int spix[2] = {0, 0}, dst4[2] = {0, 0};
    if (!consumer) {
        const int ptid = tid - NCONS;               // 0..511
        #pragma unroll
        for (int s = 0; s < 2; ++s) {
            const int idx  = ptid + s * NCONS;      // 0..1023, lane-consecutive
            const int idxe = min(idx, NV - 1);      // dummies dup slot 719 src
            const int rr   = idxe / GPR;
            const int g    = idxe - rr * GPR;
            const int yy   = min(max(gy0 + rr, 0), H - 1);
            const int xs   = min(max(gx0 + 4*g, 0), W - 4);
            spix[s] = yy * W + xs;
            dst4[s] = idx * 4;                      // dst: up to 16368 B < BUFP
        }
    }

    const int nph = C;   // CGB=1

    // consumer gather of channel c from buffer `buf`
    auto gather = [&](const float* buf, int c) {
        #pragma unroll
        for (int j = 0; j < PXT; ++j) {
            const int e = enc[j];
            if (e == -2) continue;
            if (__builtin_expect(e >= 0, 1)) {
                const float* b0 = buf + e;
                *optr[j] = a0[j]*b0[0]  + a1[j]*b0[1]
                         + a2[j]*b0[LW] + a3[j]*b0[LW+1];
            } else {
                // rare out-of-halo flow (|flow|>~4): global gather
                const int pix = pixk[j];
                const float u = flow[pix];
                const float v = flow[HW + pix];
                const int gx = pix % W;      // cheap enough on rare path
                const int gy = pix / W;
                const float x = (float)gx + u;
                const float y = (float)gy + v;
                const float x0 = floorf(x), y0f = floorf(y);
                const int x0c = (int)fminf(fmaxf(x0, 0.f), Wm1);
                const int x1c = (int)fminf(fmaxf(x0 + 1.f, 0.f), Wm1);
                const int y0c = (int)fminf(fmaxf(y0f, 0.f), Hm1);
                const int y1c = (int)fminf(fmaxf(y0f + 1.f, 0.f), Hm1);
                const float wa = (x0 + 1.f - x) * (y0f + 1.f - y);
                const float wb = (x0 + 1.f - x) * (y - y0f);
                const float wc = (x - x0) * (y0f + 1.f - y);
                const float wd = (x - x0) * (y - y0f);
                const float* ic = img + (size_t)c * HW;
                *optr[j] = wa * ic[(size_t)y0c*W + x0c]
                         + wb * ic[(size_t)y1c*W + x0c]
                         + wc * ic[(size_t)y0c*W + x1c]
                         + wd * ic[(size_t)y1c*W + x1c];
            }
            optr[j] += HW;
        }
    };

    if (fast) {
        float* bufA = &lds[0];          // consumer target (phase p)
        float* bufB = &lds[BUFP];       // phase p+1 (retiring)
        float* bufC = &lds[2*BUFP];     // producer target (phase p+2)

        // prologue: producers stage phases 0 and 1
        if (!consumer) {
            const size_t c0off = 0;
            const size_t c1off = (size_t)min(1, C-1) * HW;
            #pragma unroll
            for (int s = 0; s < 2; ++s)
                GLOAD_LDS16(img + c0off + spix[s], bufA + dst4[s]);
            #pragma unroll
            for (int s = 0; s < 2; ++s)
                GLOAD_LDS16(img + c1off + spix[s], bufB + dst4[s]);
            __builtin_amdgcn_sched_barrier(0);
            asm volatile("s_waitcnt vmcnt(2)" ::: "memory");  // D0 retired
            __builtin_amdgcn_sched_barrier(0);
        }
        __builtin_amdgcn_s_barrier();
        __builtin_amdgcn_sched_barrier(0);

        for (int p = 0; p < nph; ++p) {
            if (consumer) {
                gather(bufA, p);
            } else {
                // stage phase p+2 (clamped channel; tail dummies are L2 hits)
                const size_t coff = (size_t)min(p + 2, C - 1) * HW;
                #pragma unroll
                for (int s = 0; s < 2; ++s)
                    GLOAD_LDS16(img + coff + spix[s], bufC + dst4[s]);
                __builtin_amdgcn_sched_barrier(0);
                // per-wave vmcnt: 2 outstanding (D(p+2)) => D(p+1) retired
                asm volatile("s_waitcnt vmcnt(2)" ::: "memory");
                __builtin_amdgcn_sched_barrier(0);
            }
            __builtin_amdgcn_s_barrier();
            __builtin_amdgcn_sched_barrier(0);
            float* tmp = bufA; bufA = bufB; bufB = bufC; bufC = tmp;
        }
    } else {
        // generic slow path (partial tiles / W%4!=0): scalar stage + syncs
        for (int p = 0; p < nph; ++p) {
            __syncthreads();
            for (int i = tid; i < PLANE; i += NTHREADS) {
                const int rr = i / LW;
                const int cc = i - rr * LW;
                const int yy = min(max(gy0 + rr, 0), H - 1);
                const int xx = min(max(gx0 + cc, 0), W - 1);
                lds[i] = img[(size_t)p * HW + (size_t)yy * W + xx];
            }
            __syncthreads();
            if (consumer) gather(&lds[0], p);
        }
    }
}

extern "C" void kernel_launch(void* const* d_in, const int* in_sizes, int n_in,
                              void* d_out, int out_size, void* d_ws, size_t ws_size,
                              hipStream_t stream) {
    const float* img  = (const float*)d_in[0];
    const float* flow = (const float*)d_in[1];
    const int*   Hp   = (const int*)d_in[2];
    const int*   Wp   = (const int*)d_in[3];
    float* out = (float*)d_out;

    const int HW = in_sizes[1] / 2;    // flow is (1,2,H,W)
    const int C  = in_sizes[0] / HW;   // img is (1,C,H,W)

    // host doesn't know W,H (device scalars): launch with tile slack,
    // excess blocks exit on the in-kernel ntiles guard.
    const int grid = (HW + TSX * TSY - 1) / (TSX * TSY) + 64;
    warp_pc<<<grid, NTHREADS, 0, stream>>>(img, flow, Hp, Wp, out, HW, C);
}

// Round 16
// 182.365 us; speedup vs baseline: 1.1632x; 1.1632x over previous
//
#include <hip/hip_runtime.h>

// Bilinear backward warp, NCHW f32 — BARRIER-FREE per-wave pipelines.
// Each wave owns a 64x4 px strip and a PRIVATE ping-pong LDS pair of
// 72x12 halo'd planes (RAD=4). global_load_lds + counted vmcnt are per-wave,
// so staging(ch p+1) / gather(ch p) / store pipeline needs NO barriers at
// all — waves drift freely; 20 waves/CU overlap each other's stalls.
// R11-14 lockstep analysis: per-phase s_barrier forced all 32 waves/CU into
// alternating HBM-storm/LDS-storm (HBM 38%, LDS 25%, VALU 14%, phase time
// ~3x the throughput work). This removes the s_barrier entirely.
// vmcnt ledger per wave-phase: issue D(p+1)x4 -> wait vmcnt(8)
// (= S(p-1)x4 + D(p+1)x4; phase 0: vmcnt(4)) -> D(p) retired -> gather.
// Fallback (|flow|>~4, ~1e-4 of px) issues extra ops -> stricter waits only.
// Staging slots lane-consecutive (R10: dest = wave-uniform base + lane*16);
// dummy slots (216..255) land in the 4KB buffer pad, clamped source.

#define TSX 64
#define WROWS 4
#define NWAVES 4
#define TSY (WROWS*NWAVES)     // 16
#define RAD 4
#define LW  (TSX + 2*RAD)      // 72
#define WLH (WROWS + 2*RAD)    // 12 rows staged per wave
#define GPR (LW/4)             // 18 float4 groups per row
#define NVW (WLH*GPR)          // 216 real slots per wave-plane
#define BUFW 1024              // floats per wave buffer (4 KB, pads 256 slots)
#define NSLOT 4                // DMA slots per lane (4*64 = 256 >= 216)
#define NTHREADS 256

#define GLOAD_LDS16(g, l)                                                  \
    __builtin_amdgcn_global_load_lds(                                      \
        (const __attribute__((address_space(1))) void*)(g),                \
        (__attribute__((address_space(3))) void*)(l), 16, 0, 0)

__global__ __launch_bounds__(NTHREADS, 5) void warp_wave(
    const float* __restrict__ img,
    const float* __restrict__ flow,
    const int* __restrict__ Hp,
    const int* __restrict__ Wp,
    float* __restrict__ out,
    int HW, int C)
{
    __shared__ __align__(16) float lds[NWAVES * 2 * BUFW];   // 32 KB

    const int W = *Wp;
    const int H = *Hp;
    const int tilesX = (W + TSX - 1) / TSX;
    const int tilesY = (H + TSY - 1) / TSY;
    const int ntiles = tilesX * tilesY;
    const int bid = blockIdx.x;
    if (bid >= ntiles) return;

    // bijective XCD band swizzle
    const int q = ntiles >> 3, r = ntiles & 7;
    const int xcd = bid & 7, sub = bid >> 3;
    const int t = (xcd < r ? xcd*(q+1) : r*(q+1) + (xcd-r)*q) + sub;

    const int tileY = t / tilesX;
    const int tileX = t - tileY * tilesX;
    const int gx0 = tileX * TSX - RAD;     // ≡ 0 (mod 4)
    const int gy0 = tileY * TSY - RAD;

    const int tid  = threadIdx.x;
    const int lane = tid & 63;
    const int wv   = tid >> 6;             // wave 0..3
    const int srow = tileY * TSY + wv * WROWS;   // wave strip start row
    const int wy0  = srow - RAD;           // wave halo start row
    const int gx   = tileX * TSX + lane;

    const float Wm1 = (float)(W - 1);
    const float Hm1 = (float)(H - 1);

    // ---- per-lane precompute: 4 px (col=lane, rows srow..srow+3) ----
    float a0[WROWS], a1[WROWS], a2[WROWS], a3[WROWS];
    int enc[WROWS], pixk[WROWS];
    #pragma unroll
    for (int k = 0; k < WROWS; ++k) {
        const int gy = srow + k;
        enc[k] = -2; pixk[k] = 0;
        a0[k] = a1[k] = a2[k] = a3[k] = 0.f;
        if (gx >= W || gy >= H) continue;
        const int pix = gy * W + gx;
        pixk[k] = pix;
        const float u = flow[pix];
        const float v = flow[HW + pix];

        // normalize/denormalize round-trip omitted (identity, +-1 ulp)
        const float x = (float)gx + u;
        const float y = (float)gy + v;
        const float x0 = floorf(x), x1 = x0 + 1.0f;
        const float y0 = floorf(y), y1 = y0 + 1.0f;

        const int x0c = (int)fminf(fmaxf(x0, 0.0f), Wm1);
        const int x1c = (int)fminf(fmaxf(x1, 0.0f), Wm1);
        const int y0c = (int)fminf(fmaxf(y0, 0.0f), Hm1);
        const int y1c = (int)fminf(fmaxf(y1, 0.0f), Hm1);

        const float wa = (x1 - x) * (y1 - y);
        const float wb = (x1 - x) * (y - y0);
        const float wc = (x - x0) * (y1 - y);
        const float wd = (x - x0) * (y - y0);

        const int pbx = min(x0c, W - 2);
        const int pby = min(y0c, H - 2);

        const float wlt = (x0c == pbx ? wa : 0.f) + (x1c == pbx ? wc : 0.f);
        const float wht = (x0c != pbx ? wa : 0.f) + (x1c != pbx ? wc : 0.f);
        const float wlb = (x0c == pbx ? wb : 0.f) + (x1c == pbx ? wd : 0.f);
        const float whb = (x0c != pbx ? wb : 0.f) + (x1c != pbx ? wd : 0.f);
        const bool t0 = (y0c == pby), t1 = (y1c == pby);
        a0[k] = (t0 ? wlt : 0.f) + (t1 ? wlb : 0.f);
        a1[k] = (t0 ? wht : 0.f) + (t1 ? whb : 0.f);
        a2[k] = (t0 ? 0.f : wlt) + (t1 ? 0.f : wlb);
        a3[k] = (t0 ? 0.f : wht) + (t1 ? 0.f : whb);

        const int lxp = pbx - gx0;
        const int lyb = pby - wy0;      // wave-local halo row
        enc[k] = (lxp >= 0 && lxp <= LW-2 && lyb >= 0 && lyb <= WLH-2)
               ? (lyb * LW + lxp) : -1;
    }

    float* optr[WROWS];
    #pragma unroll
    for (int k = 0; k < WROWS; ++k) optr[k] = out + pixk[k];

    // ---- per-lane staging descriptors (4 slots, lane-consecutive) ----
    int spix[NSLOT], dst4[NSLOT];
    #pragma unroll
    for (int s = 0; s < NSLOT; ++s) {
        const int idx  = lane + s * 64;          // 0..255
        const int idxe = min(idx, NVW - 1);      // dummies clamp to slot 215
        const int rr   = idxe / GPR;
        const int g    = idxe - rr * GPR;
        const int yy   = min(max(wy0 + rr, 0), H - 1);
        const int xs   = min(max(gx0 + 4*g, 0), W - 4);  // group fully in/out
        spix[s] = yy * W + xs;
        dst4[s] = idx * 4;                        // up to 4096 B = BUFW end
    }

    const bool fast = ((W & 3) == 0) && ((tileX+1)*TSX <= W)
                   && ((tileY+1)*TSY <= H);

    // gather channel c of this wave's strip from `cur`
    auto gather = [&](const float* cur, int c) {
        #pragma unroll
        for (int k = 0; k < WROWS; ++k) {
            const int e = enc[k];
            if (e == -2) continue;
            if (__builtin_expect(e >= 0, 1)) {
                const float* b0 = cur + e;
                *optr[k] = a0[k]*b0[0]  + a1[k]*b0[1]
                         + a2[k]*b0[LW] + a3[k]*b0[LW+1];
            } else {
                // rare out-of-halo flow: recompute + global gather
                const int pix = pixk[k];
                const int gy  = srow + k;
                const float u = flow[pix];
                const float v = flow[HW + pix];
                const float x = (float)gx + u;
                const float y = (float)gy + v;
                const float x0 = floorf(x), y0f = floorf(y);
                const int x0c = (int)fminf(fmaxf(x0, 0.f), Wm1);
                const int x1c = (int)fminf(fmaxf(x0 + 1.f, 0.f), Wm1);
                const int y0c = (int)fminf(fmaxf(y0f, 0.f), Hm1);
                const int y1c = (int)fminf(fmaxf(y0f + 1.f, 0.f), Hm1);
                const float wa = (x0 + 1.f - x) * (y0f + 1.f - y);
                const float wb = (x0 + 1.f - x) * (y - y0f);
                const float wc = (x - x0) * (y0f + 1.f - y);
                const float wd = (x - x0) * (y - y0f);
                const float* ic = img + (size_t)c * HW;
                *optr[k] = wa * ic[(size_t)y0c*W + x0c]
                         + wb * ic[(size_t)y1c*W + x0c]
                         + wc * ic[(size_t)y0c*W + x1c]
                         + wd * ic[(size_t)y1c*W + x1c];
            }
            optr[k] += HW;
        }
    };

    if (fast) {
        float* cur = &lds[(wv * 2 + 0) * BUFW];
        float* nxt = &lds[(wv * 2 + 1) * BUFW];

        // prologue: stage channel 0 into cur (4 DMA instrs, this wave only)
        #pragma unroll
        for (int s = 0; s < NSLOT; ++s)
            GLOAD_LDS16(img + spix[s], cur + dst4[s]);

        for (int p = 0; p < C; ++p) {
            // issue next channel's DMA into nxt (clamped at tail: L2 hits)
            const size_t coffn = (size_t)min(p + 1, C - 1) * HW;
            #pragma unroll
            for (int s = 0; s < NSLOT; ++s)
                GLOAD_LDS16(img + coffn + spix[s], nxt + dst4[s]);
            __builtin_amdgcn_sched_barrier(0);

            // per-wave in-order vmcnt: retire D(p).
            // outstanding after D(p): S(p-1)x4 + D(p+1)x4 = 8 (phase 0: 4).
            if (p == 0) {
                asm volatile("s_waitcnt vmcnt(4)" ::: "memory");
            } else {
                asm volatile("s_waitcnt vmcnt(8)" ::: "memory");
            }
            __builtin_amdgcn_sched_barrier(0);

            gather(cur, p);        // 8 ds_read2 + 16 FMA + 4 stores

            __builtin_amdgcn_sched_barrier(0);
            float* tmp = cur; cur = nxt; nxt = tmp;
        }
    } else {
        // generic slow path (partial tiles / W%4!=0): block stages the full
        // halo'd tile plane per channel; wave-local enc offset by wv*WROWS*LW.
        const int TLH = TSY + 2 * RAD;   // 24 rows
        for (int p = 0; p < C; ++p) {
            __syncthreads();
            for (int i = tid; i < TLH * LW; i += NTHREADS) {
                const int rr = i / LW;
                const int cc = i - rr * LW;
                const int yy = min(max(gy0 + rr, 0), H - 1);
                const int xx = min(max(gx0 + cc, 0), W - 1);
                lds[i] = img[(size_t)p * HW + (size_t)yy * W + xx];
            }
            __syncthreads();
            // block-level plane: wave-local enc + wv*WROWS rows offset
            #pragma unroll
            for (int k = 0; k < WROWS; ++k) {
                const int e = enc[k];
                if (e == -2) continue;
                if (e >= 0) {
                    const float* b0 = &lds[e + wv * WROWS * LW];
                    *optr[k] = a0[k]*b0[0]  + a1[k]*b0[1]
                             + a2[k]*b0[LW] + a3[k]*b0[LW+1];
                } else {
                    const int pix = pixk[k];
                    const int gy  = srow + k;
                    const float u = flow[pix];
                    const float v = flow[HW + pix];
                    const float x = (float)gx + u;
                    const float y = (float)gy + v;
                    const float x0 = floorf(x), y0f = floorf(y);
                    const int x0c = (int)fminf(fmaxf(x0, 0.f), Wm1);
                    const int x1c = (int)fminf(fmaxf(x0 + 1.f, 0.f), Wm1);
                    const int y0c = (int)fminf(fmaxf(y0f, 0.f), Hm1);
                    const int y1c = (int)fminf(fmaxf(y0f + 1.f, 0.f), Hm1);
                    const float wa = (x0 + 1.f - x) * (y0f + 1.f - y);
                    const float wb = (x0 + 1.f - x) * (y - y0f);
                    const float wc = (x - x0) * (y0f + 1.f - y);
                    const float wd = (x - x0) * (y - y0f);
                    const float* ic = img + (size_t)p * HW;
                    *optr[k] = wa * ic[(size_t)y0c*W + x0c]
                             + wb * ic[(size_t)y1c*W + x0c]
                             + wc * ic[(size_t)y0c*W + x1c]
                             + wd * ic[(size_t)y1c*W + x1c];
                }
                optr[k] += HW;
            }
        }
    }
}

extern "C" void kernel_launch(void* const* d_in, const int* in_sizes, int n_in,
                              void* d_out, int out_size, void* d_ws, size_t ws_size,
                              hipStream_t stream) {
    const float* img  = (const float*)d_in[0];
    const float* flow = (const float*)d_in[1];
    const int*   Hp   = (const int*)d_in[2];
    const int*   Wp   = (const int*)d_in[3];
    float* out = (float*)d_out;

    const int HW = in_sizes[1] / 2;    // flow is (1,2,H,W)
    const int C  = in_sizes[0] / HW;   // img is (1,C,H,W)

    // host doesn't know W,H (device scalars): launch with tile slack,
    // excess blocks exit on the in-kernel ntiles guard.
    const int grid = (HW + TSX * TSY - 1) / (TSX * TSY) + 64;
    warp_wave<<<grid, NTHREADS, 0, stream>>>(img, flow, Hp, Wp, out, HW, C);
}

// Round 17
// 128.426 us; speedup vs baseline: 1.6518x; 1.4200x over previous
//
#include <hip/hip_runtime.h>

// Bilinear backward warp, NCHW f32 — pipelined LDS channel loop, slimmed.
// Block = 64x32 tile, 1024 threads. LDS: 2 ping-pong buffers x 2 planes of
// (72x40) RAD=4 halo'd tile (46 KB total). Per phase: issue next-phase DMA
// (global_load_lds x2/thread, descriptors precomputed ONCE), gather current
// buffer, then counted s_waitcnt vmcnt(4) + raw s_barrier (output stores stay
// in flight; the 2 oldest VM ops = our DMAs are retired by in-order vmcnt).
//
// Staging slot map is lane-consecutive per wave with no wrap (R10 lesson:
// global_load_lds writes wave-uniform base + lane*16). s=0 -> slot tid
// (0..1023), s=1 -> slot 416+tid (416..1439). All 1440 slots covered;
// 416..1023 staged twice (same src, same dst — benign).
//
// BEST KNOWN: 126.9 us (R11). R12 depth-2, R13 small-block, R14 prod/cons,
// R15 per-wave barrier-free all regressed — this structure is the floor.

#define TSX 64
#define TSY 32
#define RAD 4
#define LW  (TSX + 2*RAD)     // 72
#define LH  (TSY + 2*RAD)     // 40
#define GPR (LW/4)            // 18 float4 groups per row
#define PLANE (LW*LH)         // 2880 floats = 11520 B
#define NV  (LH*GPR)          // 720 groups per plane
#define CGB 2                 // channels per buffer
#define NSTG (CGB*NV)         // 1440 DMA slots per phase
#define NTHREADS 1024
#define SOFF (NSTG - NTHREADS)  // 416: second-slot offset

static_assert(NSTG >= NTHREADS && NSTG <= 2*NTHREADS, "2 slots per thread");

#define GLOAD_LDS16(g, l)                                                  \
    __builtin_amdgcn_global_load_lds(                                      \
        (const __attribute__((address_space(1))) void*)(g),                \
        (__attribute__((address_space(3))) void*)(l), 16, 0, 0)

__global__ __launch_bounds__(NTHREADS, 8) void warp_pipe3(
    const float* __restrict__ img,
    const float* __restrict__ flow,
    const int* __restrict__ Hp,
    const int* __restrict__ Wp,
    float* __restrict__ out,
    int HW, int C)
{
    __shared__ __align__(16) float lds[2 * CGB * PLANE];   // 46080 B

    const int W = *Wp;
    const int H = *Hp;
    const int tilesX = (W + TSX - 1) / TSX;
    const int tilesY = (H + TSY - 1) / TSY;
    const int ntiles = tilesX * tilesY;
    const int bid = blockIdx.x;
    if (bid >= ntiles) return;

    // bijective XCD band swizzle
    const int q = ntiles >> 3, r = ntiles & 7;
    const int xcd = bid & 7, sub = bid >> 3;
    const int t = (xcd < r ? xcd*(q+1) : r*(q+1) + (xcd-r)*q) + sub;

    const int tileY = t / tilesX;
    const int tileX = t - tileY * tilesX;
    const int gx0 = tileX * TSX - RAD;   // always ≡ 0 (mod 4)
    const int gy0 = tileY * TSY - RAD;

    const int tid = threadIdx.x;
    const int lx  = tid & 63;
    const int rw  = (tid >> 6) * 2;      // 2 rows per thread
    const int gx  = tileX * TSX + lx;

    const float Wm1 = (float)(W - 1);
    const float Hm1 = (float)(H - 1);

    // ---- per-pixel precompute (once per tile) ----
    float wtl[2], wth[2], wbl[2], wbh[2];
    int enc[2], pixk[2] = {0, 0};
    #pragma unroll
    for (int k = 0; k < 2; ++k) {
        const int gy = tileY * TSY + rw + k;
        enc[k] = -2;
        if (gx >= W || gy >= H) continue;
        const int pix = gy * W + gx;
        pixk[k] = pix;
        const float u = flow[pix];
        const float v = flow[HW + pix];

        // normalize/denormalize round-trip omitted (identity, +-1 ulp)
        const float x = (float)gx + u;
        const float y = (float)gy + v;
        const float x0 = floorf(x), x1 = x0 + 1.0f;
        const float y0 = floorf(y), y1 = y0 + 1.0f;

        const int x0c = (int)fminf(fmaxf(x0, 0.0f), Wm1);
        const int x1c = (int)fminf(fmaxf(x1, 0.0f), Wm1);
        const int y0c = (int)fminf(fmaxf(y0, 0.0f), Hm1);
        const int y1c = (int)fminf(fmaxf(y1, 0.0f), Hm1);

        const float wa = (x1 - x) * (y1 - y);
        const float wb = (x1 - x) * (y - y0);
        const float wc = (x - x0) * (y1 - y);
        const float wd = (x - x0) * (y - y0);

        const int pbx = min(x0c, W - 2);
        const int pby = min(y0c, H - 2);

        const float wlt = (x0c == pbx ? wa : 0.f) + (x1c == pbx ? wc : 0.f);
        const float wht = (x0c != pbx ? wa : 0.f) + (x1c != pbx ? wc : 0.f);
        const float wlb = (x0c == pbx ? wb : 0.f) + (x1c == pbx ? wd : 0.f);
        const float whb = (x0c != pbx ? wb : 0.f) + (x1c != pbx ? wd : 0.f);
        const bool t0 = (y0c == pby), t1 = (y1c == pby);
        wtl[k] = (t0 ? wlt : 0.f) + (t1 ? wlb : 0.f);
        wth[k] = (t0 ? wht : 0.f) + (t1 ? whb : 0.f);
        wbl[k] = (t0 ? 0.f : wlt) + (t1 ? 0.f : wlb);
        wbh[k] = (t0 ? 0.f : wht) + (t1 ? 0.f : whb);

        const int lxp = pbx - gx0;
        const int lyb = pby - gy0;
        enc[k] = (lxp >= 0 && lxp <= LW-2 && lyb >= 0 && lyb <= LH-2)
               ? (lyb * LW + lxp) : -1;
    }

    float* optr0 = out + pixk[0];
    float* optr1 = out + pixk[1];

    // ---- staging descriptors, computed once; lane-consecutive slots ----
    int spix[2], chrel[2], dst4[2];
    #pragma unroll
    for (int s = 0; s < 2; ++s) {
        const int idx = tid + s * SOFF;        // s=0: 0..1023, s=1: 416..1439
        const int ch  = idx / NV;
        const int rem = idx - ch * NV;
        const int rr  = rem / GPR;
        const int g   = rem - rr * GPR;
        const int yy  = min(max(gy0 + rr, 0), H - 1);
        const int xs  = min(max(gx0 + 4*g, 0), W - 4);  // group fully in/out
        chrel[s] = ch;
        spix[s]  = yy * W + xs;
        dst4[s]  = idx * 4;
    }

    const int nph = (C + CGB - 1) / CGB;
    const bool fast = ((W & 3) == 0) && ((tileX+1)*TSX <= W)
                   && ((tileY+1)*TSY <= H);

    // gather one phase from `cur`; stores via optr0/optr1
    auto gather2 = [&](const float* cur, int c0) {
        #pragma unroll
        for (int k = 0; k < 2; ++k) {
            const int e = enc[k];
            if (e == -2) continue;
            float* o = (k == 0) ? optr0 : optr1;
            if (__builtin_expect(e >= 0, 1)) {
                const float* b0 = cur + e;
                const float a0 = wtl[k], a1 = wth[k];
                const float a2 = wbl[k], a3 = wbh[k];
                o[0] = a0*b0[0] + a1*b0[1] + a2*b0[LW] + a3*b0[LW+1];
                if (c0 + 1 < C)
                    o[HW] = a0*b0[PLANE]   + a1*b0[PLANE+1]
                          + a2*b0[PLANE+LW] + a3*b0[PLANE+LW+1];
            } else {
                // rare out-of-halo flow: recompute + global gather
                const int pix = pixk[k];
                const int gy  = tileY * TSY + rw + k;
                const float u = flow[pix];
                const float v = flow[HW + pix];
                const float x = (float)gx + u;
                const float y = (float)gy + v;
                const float x0 = floorf(x), y0f = floorf(y);
                const int x0c = (int)fminf(fmaxf(x0, 0.f), Wm1);
                const int x1c = (int)fminf(fmaxf(x0 + 1.f, 0.f), Wm1);
                const int y0c = (int)fminf(fmaxf(y0f, 0.f), Hm1);
                const int y1c = (int)fminf(fmaxf(y0f + 1.f, 0.f), Hm1);
                const float wa = (x0 + 1.f - x) * (y0f + 1.f - y);
                const float wb = (x0 + 1.f - x) * (y - y0f);
                const float wc = (x - x0) * (y0f + 1.f - y);
                const float wd = (x - x0) * (y - y0f);
                for (int c = 0; c < CGB && c0 + c < C; ++c) {
                    const float* ic = img + (size_t)(c0 + c) * HW;
                    o[(size_t)c * HW] =
                          wa * ic[(size_t)y0c*W + x0c] + wb * ic[(size_t)y1c*W + x0c]
                        + wc * ic[(size_t)y0c*W + x1c] + wd * ic[(size_t)y1c*W + x1c];
                }
            }
        }
    };

    if (fast) {
        // prologue: stage phase 0 into buffer A
        #pragma unroll
        for (int s = 0; s < 2; ++s) {
            const int chc = min(chrel[s], C - 1);
            GLOAD_LDS16(img + (size_t)chc * HW + spix[s], &lds[dst4[s]]);
        }
        asm volatile("s_waitcnt vmcnt(0)" ::: "memory");
        __builtin_amdgcn_s_barrier();
        __builtin_amdgcn_sched_barrier(0);

        float* cur = &lds[0];
        float* nxt = &lds[CGB * PLANE];

        for (int p = 0; p < nph; ++p) {
            const int c0 = p * CGB;

            if (p + 1 < nph) {   // issue DMA for next phase FIRST
                const int c0n = c0 + CGB;
                #pragma unroll
                for (int s = 0; s < 2; ++s) {
                    const int chc = min(c0n + chrel[s], C - 1);
                    GLOAD_LDS16(img + (size_t)chc * HW + spix[s], nxt + dst4[s]);
                }
            }
            __builtin_amdgcn_sched_barrier(0);   // pin: DMAs before stores

            gather2(cur, c0);                    // 4 stores per thread

            __builtin_amdgcn_sched_barrier(0);   // pin: stores before wait

            if (p + 1 < nph) {
                // in-order vmcnt: count<=4 => the 2 oldest (our DMAs) retired;
                // the 4 output stores stay in flight across the barrier.
                asm volatile("s_waitcnt vmcnt(4)" ::: "memory");
                __builtin_amdgcn_sched_barrier(0);
                __builtin_amdgcn_s_barrier();
                __builtin_amdgcn_sched_barrier(0);
            }
            float* tmp = cur; cur = nxt; nxt = tmp;
            optr0 += (size_t)CGB * HW;
            optr1 += (size_t)CGB * HW;
        }
    } else {
        // generic slow path (partial tiles / W%4!=0): scalar stage + full syncs
        for (int p = 0; p < nph; ++p) {
            const int c0 = p * CGB;
            __syncthreads();
            for (int i = tid; i < CGB * PLANE; i += NTHREADS) {
                const int ch  = i / PLANE;
                const int rem = i - ch * PLANE;
                const int rr  = rem / LW;
                const int cc  = rem - rr * LW;
                const int yy  = min(max(gy0 + rr, 0), H - 1);
                const int xx  = min(max(gx0 + cc, 0), W - 1);
                const int chc = min(c0 + ch, C - 1);
                lds[i] = img[(size_t)chc * HW + (size_t)yy * W + xx];
            }
            __syncthreads();
            gather2(&lds[0], c0);
            optr0 += (size_t)CGB * HW;
            optr1 += (size_t)CGB * HW;
        }
    }
}

extern "C" void kernel_launch(void* const* d_in, const int* in_sizes, int n_in,
                              void* d_out, int out_size, void* d_ws, size_t ws_size,
                              hipStream_t stream) {
    const float* img  = (const float*)d_in[0];
    const float* flow = (const float*)d_in[1];
    const int*   Hp   = (const int*)d_in[2];
    const int*   Wp   = (const int*)d_in[3];
    float* out = (float*)d_out;

    const int HW = in_sizes[1] / 2;    // flow is (1,2,H,W)
    const int C  = in_sizes[0] / HW;   // img is (1,C,H,W)

    // host doesn't know W,H (device scalars): launch with tile slack,
    // excess blocks exit on the in-kernel ntiles guard.
    const int grid = (HW + TSX * TSY - 1) / (TSX * TSY) + 64;
    warp_pipe3<<<grid, NTHREADS, 0, stream>>>(img, flow, Hp, Wp, out, HW, C);
}